// Round 1
// baseline (688.484 us; speedup 1.0000x reference)
//
#include <hip/hip_runtime.h>
#include <math.h>

// Problem constants
#define B_   8
#define C_   64      // Ci = Cc = 64, fused input channels = 128
#define H_   128
#define W_   128
#define HW_  16384   // H_*W_
#define K2_  9

// Workspace layout (floats):
//   wfT  [128][64]            @ 0          (8192)
//   wrT  [9][64][64]          @ 8192       (36864)
//   xt   [B][H][W][64] (NHWC) @ 45056      (8388608)
//   om   [B][H][W][28]        @ 8433664    (3670016)  per-pixel: dy[9], dx[9], mod[9], pad
#define WS_WFT  0
#define WS_WRT  8192
#define WS_XT   45056
#define WS_OM   8433664

// ---------------------------------------------------------------------------
// Kernel 0: pack/transpose weights.
//   wfT[i*64+o]          = w_fuse[o*128+i]
//   wrT[(k*64+i)*64+o]   = w_reg[(o*64+i)*9+k]
// ---------------------------------------------------------------------------
__global__ __launch_bounds__(256) void k_pack(const float* __restrict__ wf,
                                              const float* __restrict__ wreg,
                                              float* __restrict__ wfT,
                                              float* __restrict__ wrT) {
    int idx = blockIdx.x * 256 + threadIdx.x;
    if (idx < 8192) {
        int o = idx & 63, i = idx >> 6;
        wfT[idx] = wf[o * 128 + i];
    }
    int j = idx - 8192;
    if (j >= 0 && j < 36864) {
        int o = j & 63, i = (j >> 6) & 63, k = j >> 12;
        wrT[j] = wreg[(o * 64 + i) * 9 + k];
    }
}

// ---------------------------------------------------------------------------
// Kernel 1: 1x1 fuse conv, NCHW inputs -> NHWC output xt.
//   xt[b][p][o] = sum_i wfT[i][o] * cat[b][i][p]
// Block: 256 threads, 32 pixels per block. grid = B_ * (HW_/32) = 4096.
// ---------------------------------------------------------------------------
__global__ __launch_bounds__(256) void k_fuse(const float* __restrict__ xi,
                                              const float* __restrict__ xc,
                                              const float* __restrict__ wfT,
                                              float* __restrict__ xt) {
    __shared__ float sW[128 * 64];    // [i][o]
    __shared__ float sIn[128 * 32];   // [i][px]
    const int t = threadIdx.x;
    const int b = blockIdx.x >> 9;
    const int px0 = (blockIdx.x & 511) * 32;

    // stage weights (coalesced float4)
    {
        const float4* s = (const float4*)wfT;
        float4* d = (float4*)sW;
#pragma unroll
        for (int j = 0; j < 8; ++j) d[t + 256 * j] = s[t + 256 * j];
    }
    // stage inputs: 128 ch x 32 px = 1024 float4
    {
        float4* d = (float4*)sIn;
#pragma unroll
        for (int j = 0; j < 4; ++j) {
            int idx4 = t + 256 * j;
            int i = idx4 >> 3;
            int p4 = (idx4 & 7) << 2;
            const float* src = (i < 64)
                ? (xi + ((size_t)(b * 64 + i)) * HW_ + px0 + p4)
                : (xc + ((size_t)(b * 64 + (i - 64))) * HW_ + px0 + p4);
            d[idx4] = *(const float4*)src;
        }
    }
    __syncthreads();

    const int o = t & 63;
    const int q = t >> 6;   // wave id -> 8-pixel group
    float acc[8];
#pragma unroll
    for (int j = 0; j < 8; ++j) acc[j] = 0.f;

    for (int i = 0; i < 128; ++i) {
        const float w = sW[i * 64 + o];
        const float4 a = *(const float4*)&sIn[i * 32 + q * 8];
        const float4 c = *(const float4*)&sIn[i * 32 + q * 8 + 4];
        acc[0] += w * a.x; acc[1] += w * a.y; acc[2] += w * a.z; acc[3] += w * a.w;
        acc[4] += w * c.x; acc[5] += w * c.y; acc[6] += w * c.z; acc[7] += w * c.w;
    }

    float* dst = xt + ((size_t)b * HW_ + px0 + q * 8) * 64 + o;
#pragma unroll
    for (int j = 0; j < 8; ++j) dst[(size_t)j * 64] = acc[j];
}

// ---------------------------------------------------------------------------
// Kernel 2: 3x3 convs producing off (18ch) + mod (9ch), writes om records.
// Block: 256 threads = 16x16 spatial tile. grid = B_*8*8 = 512.
// ---------------------------------------------------------------------------
__global__ __launch_bounds__(256) void k_offmod(const float* __restrict__ xt,
                                                const float* __restrict__ wOff,
                                                const float* __restrict__ bOff,
                                                const float* __restrict__ wMod,
                                                const float* __restrict__ bMod,
                                                float* __restrict__ om) {
    __shared__ float sX[16 * 324];   // [ch in chunk][18*18 tile]
    const int t = threadIdx.x;
    const int bb = blockIdx.x >> 6;
    const int ty = (blockIdx.x >> 3) & 7;
    const int tx = blockIdx.x & 7;
    const int y0 = ty * 16, x0 = tx * 16;
    const int xx = t & 15, yy = t >> 4;

    float accO[18], accM[9];
#pragma unroll
    for (int c = 0; c < 18; ++c) accO[c] = 0.f;
#pragma unroll
    for (int c = 0; c < 9; ++c) accM[c] = 0.f;

    for (int c0 = 0; c0 < 64; c0 += 16) {
        __syncthreads();
        for (int idx = t; idx < 16 * 324; idx += 256) {
            int ch = idx & 15, p = idx >> 4;
            int pyy = y0 + (p / 18) - 1;
            int pxx = x0 + (p % 18) - 1;
            float v = 0.f;
            if (pyy >= 0 && pyy < H_ && pxx >= 0 && pxx < W_)
                v = xt[(((size_t)bb * H_ + pyy) * W_ + pxx) * 64 + c0 + ch];
            sX[ch * 324 + p] = v;
        }
        __syncthreads();

        for (int i = 0; i < 16; ++i) {
            const int ci = c0 + i;
#pragma unroll
            for (int tap = 0; tap < 9; ++tap) {
                const int kyy = tap / 3, kxx = tap % 3;
                const float v = sX[i * 324 + (yy + kyy) * 18 + xx + kxx];
#pragma unroll
                for (int c = 0; c < 18; ++c)
                    accO[c] += wOff[(c * 64 + ci) * 9 + tap] * v;
#pragma unroll
                for (int c = 0; c < 9; ++c)
                    accM[c] += wMod[(c * 64 + ci) * 9 + tap] * v;
            }
        }
    }

    const size_t rec = (((size_t)bb * H_ + (y0 + yy)) * W_ + (x0 + xx)) * 28;
#pragma unroll
    for (int k = 0; k < 9; ++k) {
        om[rec + k]     = accO[2 * k]     + bOff[2 * k];
        om[rec + 9 + k] = accO[2 * k + 1] + bOff[2 * k + 1];
        const float z = accM[k] + bMod[k];
        om[rec + 18 + k] = 2.f / (1.f + expf(-z));
    }
}

// ---------------------------------------------------------------------------
// Kernel 3: deformable bilinear sampling + modulation + einsum.
// Block: 256 threads (4 waves), one (b, y) row of 128 pixels.
// grid = B_ * H_ = 1024.
// LDS: sS[i][px] stride 132 (b128-aligned reads along px),
//      sW[i][o] for current tap k.
// Thread FMA blocking: 8 outputs x 4 pixels.
// ---------------------------------------------------------------------------
__global__ __launch_bounds__(256) void k_deform(const float* __restrict__ xt,
                                                const float* __restrict__ om,
                                                const float* __restrict__ wrT,
                                                float* __restrict__ out) {
    __shared__ float sS[64 * 132];   // s[i][px], px stride 132
    __shared__ float sW[64 * 64];    // w[i][o] for current k
    const int t = threadIdx.x;
    const int lane = t & 63;
    const int wv = t >> 6;
    const int b = blockIdx.x >> 7;
    const int y = blockIdx.x & 127;

    const int og = lane & 7;           // output-channel group (8 ch)
    const int pg = lane >> 3;          // pixel group (4 px) within wave
    const int obase = og * 8;
    const int px0 = wv * 32 + pg * 4;

    const float* xb = xt + (size_t)b * HW_ * 64;
    const float* omrow = om + ((size_t)(b * H_ + y)) * W_ * 28;

    float acc[32];
#pragma unroll
    for (int j = 0; j < 32; ++j) acc[j] = 0.f;

    for (int k = 0; k < 9; ++k) {
        // stage this tap's weights: wrT + k*4096, 1024 float4
        {
            const float4* s = (const float4*)(wrT + (size_t)k * 4096);
            float4* d = (float4*)sW;
#pragma unroll
            for (int j = 0; j < 4; ++j) d[t + 256 * j] = s[t + 256 * j];
        }
        // sampling: lane = channel, wave wv covers px [wv*32, wv*32+32)
        const int ky = k / 3 - 1, kx = k % 3 - 1;
        for (int p = 0; p < 32; ++p) {
            const int px = wv * 32 + p;
            const float* r = omrow + px * 28;
            const float dy = r[k], dx = r[9 + k], m = r[18 + k];
            const float py  = (float)(y + ky) + dy;
            const float pxe = (float)(px + kx) + dx;
            const float y0f = floorf(py), x0f = floorf(pxe);
            const int y0i = (int)y0f, x0i = (int)x0f;
            const float wy1 = py - y0f, wx1 = pxe - x0f;
            const float wy0 = 1.f - wy1, wx0 = 1.f - wx1;
            float v = 0.f;
#pragma unroll
            for (int c = 0; c < 4; ++c) {
                const int yyi = y0i + (c >> 1);
                const int xxi = x0i + (c & 1);
                const bool ok = (yyi >= 0) && (yyi < H_) && (xxi >= 0) && (xxi < W_);
                const int yc = min(max(yyi, 0), H_ - 1);
                const int xc = min(max(xxi, 0), W_ - 1);
                const float g = xb[((size_t)(yc * W_ + xc)) * 64 + lane];
                const float wgt = ((c >> 1) ? wy1 : wy0) * ((c & 1) ? wx1 : wx0);
                v += ok ? g * wgt : 0.f;
            }
            sS[lane * 132 + px] = v * m;
        }
        __syncthreads();

        // einsum partial: acc[oo][j] += w[i][obase+oo] * s[i][px0+j]
        for (int i = 0; i < 64; ++i) {
            const float4 w0 = *(const float4*)&sW[i * 64 + obase];
            const float4 w1 = *(const float4*)&sW[i * 64 + obase + 4];
            const float4 sv = *(const float4*)&sS[i * 132 + px0];
            const float wa[8] = {w0.x, w0.y, w0.z, w0.w, w1.x, w1.y, w1.z, w1.w};
            const float sa[4] = {sv.x, sv.y, sv.z, sv.w};
#pragma unroll
            for (int oo = 0; oo < 8; ++oo)
#pragma unroll
                for (int j = 0; j < 4; ++j)
                    acc[oo * 4 + j] += wa[oo] * sa[j];
        }
        __syncthreads();
    }

    // epilogue: out is NCHW
#pragma unroll
    for (int oo = 0; oo < 8; ++oo) {
        float4 v;
        v.x = acc[oo * 4 + 0]; v.y = acc[oo * 4 + 1];
        v.z = acc[oo * 4 + 2]; v.w = acc[oo * 4 + 3];
        float* dst = out + (((size_t)(b * 64 + obase + oo) * H_ + y) * W_ + px0);
        *(float4*)dst = v;
    }
}

// ---------------------------------------------------------------------------
extern "C" void kernel_launch(void* const* d_in, const int* in_sizes, int n_in,
                              void* d_out, int out_size, void* d_ws, size_t ws_size,
                              hipStream_t stream) {
    const float* x_img  = (const float*)d_in[0];
    const float* x_cont = (const float*)d_in[1];
    const float* w_fuse = (const float*)d_in[2];
    const float* w_off  = (const float*)d_in[3];
    const float* b_off  = (const float*)d_in[4];
    const float* w_mod  = (const float*)d_in[5];
    const float* b_mod  = (const float*)d_in[6];
    const float* w_reg  = (const float*)d_in[7];
    float* out = (float*)d_out;

    float* ws  = (float*)d_ws;
    float* wfT = ws + WS_WFT;
    float* wrT = ws + WS_WRT;
    float* xt  = ws + WS_XT;
    float* om  = ws + WS_OM;

    k_pack<<<176, 256, 0, stream>>>(w_fuse, w_reg, wfT, wrT);
    k_fuse<<<B_ * (HW_ / 32), 256, 0, stream>>>(x_img, x_cont, wfT, xt);
    k_offmod<<<B_ * 8 * 8, 256, 0, stream>>>(xt, w_off, b_off, w_mod, b_mod, om);
    k_deform<<<B_ * H_, 256, 0, stream>>>(xt, om, wrT, out);
}

// Round 2
// 557.947 us; speedup vs baseline: 1.2340x; 1.2340x over previous
//
#include <hip/hip_runtime.h>
#include <math.h>

// Problem constants
#define B_   8
#define C_   64
#define H_   128
#define W_   128
#define HW_  16384
#define K2_  9

typedef float f32x4 __attribute__((ext_vector_type(4)));
typedef short bf16x8 __attribute__((ext_vector_type(8)));

// Workspace layout (float offsets):
//   wfT  [128][64]              @ 0        (8192 f)
//   wrP  bf16 frag-packed       @ 8192     (36864 ushort = 18432 f)
//   xt   [B][H][W][64] (NHWC)   @ 45056    (8388608 f)
//   om   [B][H][W][28]          @ 8433664  (3670016 f)
#define WS_WFT  0
#define WS_WRP  8192
#define WS_XT   45056
#define WS_OM   8433664

static __device__ __forceinline__ unsigned short f2bf(float x) {
    unsigned int u = __float_as_uint(x);
    unsigned int r = (u + 0x7fffu + ((u >> 16) & 1u)) >> 16;   // RNE
    return (unsigned short)r;
}

// ---------------------------------------------------------------------------
// Kernel 0: pack weights.
//   wfT[i*64+o] = w_fuse[o*128+i]
//   wrP: bf16 A-fragments for mfma_f32_16x16x32_bf16, per-lane packed:
//     frag f = ((tap*2 + kc)*4 + mt)*64 + lane holds 8 bf16:
//       o = mt*16 + (lane&15); i = kc*32 + (lane>>4)*8 + j
//       val = w_reg[(o*64 + i)*9 + tap]
// ---------------------------------------------------------------------------
__global__ __launch_bounds__(256) void k_pack(const float* __restrict__ wf,
                                              const float* __restrict__ wreg,
                                              float* __restrict__ wfT,
                                              unsigned short* __restrict__ wrP) {
    int idx = blockIdx.x * 256 + threadIdx.x;
    if (idx < 8192) {
        int o = idx & 63, i = idx >> 6;
        wfT[idx] = wf[o * 128 + i];
    }
    if (idx < 4608) {
        int lane = idx & 63, mt = (idx >> 6) & 3, kc = (idx >> 8) & 1, tap = idx >> 9;
        int o = mt * 16 + (lane & 15);
        int ibase = kc * 32 + (lane >> 4) * 8;
#pragma unroll
        for (int j = 0; j < 8; ++j)
            wrP[idx * 8 + j] = f2bf(wreg[(o * 64 + ibase + j) * 9 + tap]);
    }
}

// ---------------------------------------------------------------------------
// Kernel 1: 1x1 fuse conv, NCHW inputs -> NHWC xt. 32 px/block, grid 4096.
// blockIdx = p*8 + b  (batch -> XCD swizzle)
// ---------------------------------------------------------------------------
__global__ __launch_bounds__(256) void k_fuse(const float* __restrict__ xi,
                                              const float* __restrict__ xc,
                                              const float* __restrict__ wfT,
                                              float* __restrict__ xt) {
    __shared__ float sW[128 * 64];
    __shared__ float sIn[128 * 32];
    const int t = threadIdx.x;
    const int b = blockIdx.x & 7;
    const int px0 = (blockIdx.x >> 3) * 32;

    {
        const float4* s = (const float4*)wfT;
        float4* d = (float4*)sW;
#pragma unroll
        for (int j = 0; j < 8; ++j) d[t + 256 * j] = s[t + 256 * j];
    }
    {
        float4* d = (float4*)sIn;
#pragma unroll
        for (int j = 0; j < 4; ++j) {
            int idx4 = t + 256 * j;
            int i = idx4 >> 3;
            int p4 = (idx4 & 7) << 2;
            const float* src = (i < 64)
                ? (xi + ((size_t)(b * 64 + i)) * HW_ + px0 + p4)
                : (xc + ((size_t)(b * 64 + (i - 64))) * HW_ + px0 + p4);
            d[idx4] = *(const float4*)src;
        }
    }
    __syncthreads();

    const int o = t & 63;
    const int q = t >> 6;
    float acc[8];
#pragma unroll
    for (int j = 0; j < 8; ++j) acc[j] = 0.f;

    for (int i = 0; i < 128; ++i) {
        const float w = sW[i * 64 + o];
        const float4 a = *(const float4*)&sIn[i * 32 + q * 8];
        const float4 c = *(const float4*)&sIn[i * 32 + q * 8 + 4];
        acc[0] += w * a.x; acc[1] += w * a.y; acc[2] += w * a.z; acc[3] += w * a.w;
        acc[4] += w * c.x; acc[5] += w * c.y; acc[6] += w * c.z; acc[7] += w * c.w;
    }

    float* dst = xt + ((size_t)b * HW_ + px0 + q * 8) * 64 + o;
#pragma unroll
    for (int j = 0; j < 8; ++j) dst[(size_t)j * 64] = acc[j];
}

// ---------------------------------------------------------------------------
// Kernel 2: 3x3 convs -> off(18)+mod(9) per pixel, om records.
// 16x16 tile, grid 512, blockIdx = tile*8 + b (XCD swizzle).
// Weights staged in LDS per 16-channel chunk (broadcast reads).
// ---------------------------------------------------------------------------
__global__ __launch_bounds__(256) void k_offmod(const float* __restrict__ xt,
                                                const float* __restrict__ wOff,
                                                const float* __restrict__ bOff,
                                                const float* __restrict__ wMod,
                                                const float* __restrict__ bMod,
                                                float* __restrict__ om) {
    __shared__ float sX[16 * 324];     // 20736 B
    __shared__ float sWo[18 * 144];    // 10368 B
    __shared__ float sWm[9 * 144];     //  5184 B
    const int t = threadIdx.x;
    const int bb = blockIdx.x & 7;
    const int tile = blockIdx.x >> 3;
    const int ty = tile >> 3, tx = tile & 7;
    const int y0 = ty * 16, x0 = tx * 16;
    const int xx = t & 15, yy = t >> 4;

    float accO[18], accM[9];
#pragma unroll
    for (int c = 0; c < 18; ++c) accO[c] = 0.f;
#pragma unroll
    for (int c = 0; c < 9; ++c) accM[c] = 0.f;

    for (int c0 = 0; c0 < 64; c0 += 16) {
        __syncthreads();
        for (int idx = t; idx < 16 * 324; idx += 256) {
            int ch = idx & 15, p = idx >> 4;
            int pyy = y0 + (p / 18) - 1;
            int pxx = x0 + (p % 18) - 1;
            float v = 0.f;
            if (pyy >= 0 && pyy < H_ && pxx >= 0 && pxx < W_)
                v = xt[(((size_t)bb * H_ + pyy) * W_ + pxx) * 64 + c0 + ch];
            sX[ch * 324 + p] = v;
        }
        for (int idx = t; idx < 2592; idx += 256) {
            int c = idx / 144, r = idx - c * 144;
            sWo[idx] = wOff[(c * 64 + c0) * 9 + r];
        }
        for (int idx = t; idx < 1296; idx += 256) {
            int c = idx / 144, r = idx - c * 144;
            sWm[idx] = wMod[(c * 64 + c0) * 9 + r];
        }
        __syncthreads();

        for (int i = 0; i < 16; ++i) {
#pragma unroll
            for (int tap = 0; tap < 9; ++tap) {
                const int kyy = tap / 3, kxx = tap % 3;
                const float v = sX[i * 324 + (yy + kyy) * 18 + xx + kxx];
#pragma unroll
                for (int c = 0; c < 18; ++c)
                    accO[c] += sWo[c * 144 + i * 9 + tap] * v;
#pragma unroll
                for (int c = 0; c < 9; ++c)
                    accM[c] += sWm[c * 144 + i * 9 + tap] * v;
            }
        }
    }

    const size_t rec = (((size_t)bb * H_ + (y0 + yy)) * W_ + (x0 + xx)) * 28;
#pragma unroll
    for (int k = 0; k < 9; ++k) {
        om[rec + k]     = accO[2 * k]     + bOff[2 * k];
        om[rec + 9 + k] = accO[2 * k + 1] + bOff[2 * k + 1];
        const float z = accM[k] + bMod[k];
        om[rec + 18 + k] = 2.f / (1.f + expf(-z));
    }
}

// ---------------------------------------------------------------------------
// Kernel 3: deformable sampling + modulation + bf16 MFMA einsum.
// Block: 256 thr (4 waves), one (b,y) row of 128 px. grid 1024,
// blockIdx = y*8 + b (batch -> XCD swizzle; xt fits one XCD L2).
// Wave wv owns px [wv*32, wv*32+32): samples them (lane=channel) into LDS
// in B-fragment order, then runs 16x16x32 bf16 MFMA; no cross-wave deps,
// so no barriers in the tap loop.
// sS2: [g=0..7][px=0..127][8 bf16], g = i>>3; block stride padded to 1032 us.
// ---------------------------------------------------------------------------
__global__ __launch_bounds__(256) void k_deform(const float* __restrict__ xt,
                                                const float* __restrict__ om,
                                                const unsigned short* __restrict__ wrP,
                                                float* __restrict__ out) {
    __shared__ unsigned short sS2[8 * 1032];   // 16512 B
    __shared__ float sOM[3584];                // 14336 B
    const int t = threadIdx.x;
    const int lane = t & 63;
    const int wv = t >> 6;
    const int b = blockIdx.x & 7;
    const int y = blockIdx.x >> 3;

    const float* xb = xt + (size_t)b * HW_ * 64;

    // stage om row (128 px * 28 floats)
    {
        const float4* src = (const float4*)(om + ((size_t)(b * H_ + y)) * W_ * 28);
        float4* dst = (float4*)sOM;
        for (int idx = t; idx < 896; idx += 256) dst[idx] = src[idx];
    }
    __syncthreads();

    const int n15 = lane & 15;
    const int q4 = lane >> 4;
    const int wpx = wv * 32;
    const int g = lane >> 3;          // B-frag row group for sampling writes
    const int j7 = lane & 7;

    f32x4 acc[4][2];
#pragma unroll
    for (int mt = 0; mt < 4; ++mt)
#pragma unroll
        for (int nt = 0; nt < 2; ++nt)
            acc[mt][nt] = (f32x4){0.f, 0.f, 0.f, 0.f};

    for (int k = 0; k < 9; ++k) {
        // A-fragments for this tap: 8 x 16B from global (L1/L2 cached)
        bf16x8 afr[2][4];
#pragma unroll
        for (int kc = 0; kc < 2; ++kc)
#pragma unroll
            for (int mt = 0; mt < 4; ++mt)
                afr[kc][mt] = *(const bf16x8*)(wrP +
                    ((((size_t)((k * 2 + kc) * 4 + mt)) * 64 + lane) * 8));

        const int ky = k / 3 - 1, kx = k % 3 - 1;
#pragma unroll 2
        for (int p = 0; p < 32; ++p) {
            const int px = wpx + p;
            const float dy = sOM[px * 28 + k];
            const float dxv = sOM[px * 28 + 9 + k];
            const float m = sOM[px * 28 + 18 + k];
            const float py  = (float)(y + ky) + dy;
            const float pxe = (float)(px + kx) + dxv;
            const float y0f = floorf(py), x0f = floorf(pxe);
            const int y0i = (int)y0f, x0i = (int)x0f;
            const float wy1 = py - y0f, wx1 = pxe - x0f;
            const float wy0 = 1.f - wy1, wx0 = 1.f - wx1;
            float v = 0.f;
#pragma unroll
            for (int c = 0; c < 4; ++c) {
                const int yyi = y0i + (c >> 1);
                const int xxi = x0i + (c & 1);
                const bool ok = (yyi >= 0) && (yyi < H_) && (xxi >= 0) && (xxi < W_);
                const int yc = min(max(yyi, 0), H_ - 1);
                const int xc = min(max(xxi, 0), W_ - 1);
                const float gv = xb[((size_t)(yc * W_ + xc)) * 64 + lane];
                const float wgt = ((c >> 1) ? wy1 : wy0) * ((c & 1) ? wx1 : wx0);
                v += ok ? gv * wgt : 0.f;
            }
            sS2[g * 1032 + px * 8 + j7] = f2bf(v * m);
        }

        // MFMA: B-frags read only this wave's px range (intra-wave dep only)
#pragma unroll
        for (int kc = 0; kc < 2; ++kc) {
            const bf16x8 b0 = *(const bf16x8*)&sS2[(kc * 4 + q4) * 1032 + (wpx + n15) * 8];
            const bf16x8 b1 = *(const bf16x8*)&sS2[(kc * 4 + q4) * 1032 + (wpx + 16 + n15) * 8];
#pragma unroll
            for (int mt = 0; mt < 4; ++mt) {
                acc[mt][0] = __builtin_amdgcn_mfma_f32_16x16x32_bf16(afr[kc][mt], b0, acc[mt][0], 0, 0, 0);
                acc[mt][1] = __builtin_amdgcn_mfma_f32_16x16x32_bf16(afr[kc][mt], b1, acc[mt][1], 0, 0, 0);
            }
        }
    }

    // epilogue: D[o = mt*16 + q4*4 + r][px = wpx + nt*16 + n15], out NCHW
#pragma unroll
    for (int mt = 0; mt < 4; ++mt)
#pragma unroll
        for (int nt = 0; nt < 2; ++nt) {
            const int px = wpx + nt * 16 + n15;
#pragma unroll
            for (int r = 0; r < 4; ++r) {
                const int o = mt * 16 + q4 * 4 + r;
                out[(((size_t)(b * 64 + o)) * H_ + y) * W_ + px] = acc[mt][nt][r];
            }
        }
}

// ---------------------------------------------------------------------------
extern "C" void kernel_launch(void* const* d_in, const int* in_sizes, int n_in,
                              void* d_out, int out_size, void* d_ws, size_t ws_size,
                              hipStream_t stream) {
    const float* x_img  = (const float*)d_in[0];
    const float* x_cont = (const float*)d_in[1];
    const float* w_fuse = (const float*)d_in[2];
    const float* w_off  = (const float*)d_in[3];
    const float* b_off  = (const float*)d_in[4];
    const float* w_mod  = (const float*)d_in[5];
    const float* b_mod  = (const float*)d_in[6];
    const float* w_reg  = (const float*)d_in[7];
    float* out = (float*)d_out;

    float* ws  = (float*)d_ws;
    float* wfT = ws + WS_WFT;
    unsigned short* wrP = (unsigned short*)(ws + WS_WRP);
    float* xt  = ws + WS_XT;
    float* om  = ws + WS_OM;

    k_pack<<<32, 256, 0, stream>>>(w_fuse, w_reg, wfT, wrP);
    k_fuse<<<B_ * (HW_ / 32), 256, 0, stream>>>(x_img, x_cont, wfT, xt);
    k_offmod<<<B_ * 8 * 8, 256, 0, stream>>>(xt, w_off, b_off, w_mod, b_mod, om);
    k_deform<<<B_ * H_, 256, 0, stream>>>(xt, om, wrP, out);
}

// Round 3
// 372.988 us; speedup vs baseline: 1.8459x; 1.4959x over previous
//
#include <hip/hip_runtime.h>
#include <math.h>

// Problem constants
#define B_   8
#define C_   64
#define H_   128
#define W_   128
#define HW_  16384
#define K2_  9

typedef float f32x4 __attribute__((ext_vector_type(4)));
typedef short bf16x8 __attribute__((ext_vector_type(8)));

// Workspace layout (float offsets):
//   wfT  [128][64]              @ 0        (8192 f)
//   wrP  deform A-frags bf16    @ 8192     (36864 us = 18432 f)
//   wrP2 offmod A-frags bf16    @ 26624    (18432 us = 9216 f)
//   xt   [B][H][W][64] (NHWC)   @ 45056    (8388608 f)
//   om   [B][H][W][28]          @ 8433664  (3670016 f)
#define WS_WFT  0
#define WS_WRP  8192
#define WS_WRP2 26624
#define WS_XT   45056
#define WS_OM   8433664

static __device__ __forceinline__ unsigned short f2bf(float x) {
    unsigned int u = __float_as_uint(x);
    unsigned int r = (u + 0x7fffu + ((u >> 16) & 1u)) >> 16;   // RNE
    return (unsigned short)r;
}

// ---------------------------------------------------------------------------
// Kernel 0: pack weights.
//   wfT[i*64+o] = w_fuse[o*128+i]
//   wrP  : deform einsum A-frags (16x16x32 bf16), frag (tap,kc,mt):
//          o = mt*16+(lane&15); i = kc*32+(lane>>4)*8+j
//   wrP2 : offmod conv A-frags, K-order k = tap*64+ci, frag (kc 0..17, mt 0..1):
//          m = mt*16+(lane&15); gk = kc*32+(lane>>4)*8+j; tap=gk>>6; ci=gk&63
//          m<18 -> w_off[(m*64+ci)*9+tap]; m<27 -> w_mod[((m-18)*64+ci)*9+tap]; else 0
// ---------------------------------------------------------------------------
__global__ __launch_bounds__(256) void k_pack(const float* __restrict__ wf,
                                              const float* __restrict__ wreg,
                                              const float* __restrict__ wOff,
                                              const float* __restrict__ wMod,
                                              float* __restrict__ wfT,
                                              unsigned short* __restrict__ wrP,
                                              unsigned short* __restrict__ wrP2) {
    int idx = blockIdx.x * 256 + threadIdx.x;
    if (idx < 8192) {
        int o = idx & 63, i = idx >> 6;
        wfT[idx] = wf[o * 128 + i];
    }
    if (idx < 4608) {
        int lane = idx & 63, mt = (idx >> 6) & 3, kc = (idx >> 8) & 1, tap = idx >> 9;
        int o = mt * 16 + (lane & 15);
        int ibase = kc * 32 + (lane >> 4) * 8;
#pragma unroll
        for (int j = 0; j < 8; ++j)
            wrP[idx * 8 + j] = f2bf(wreg[(o * 64 + ibase + j) * 9 + tap]);
    }
    if (idx < 2304) {
        int lane = idx & 63, mt = (idx >> 6) & 1, kc = idx >> 7;
        int m = mt * 16 + (lane & 15);
        int gkb = kc * 32 + (lane >> 4) * 8;
#pragma unroll
        for (int j = 0; j < 8; ++j) {
            int gk = gkb + j, tap = gk >> 6, ci = gk & 63;
            float v = 0.f;
            if (m < 18)      v = wOff[(m * 64 + ci) * 9 + tap];
            else if (m < 27) v = wMod[((m - 18) * 64 + ci) * 9 + tap];
            wrP2[idx * 8 + j] = f2bf(v);
        }
    }
}

// ---------------------------------------------------------------------------
// Kernel 1: 1x1 fuse conv, NCHW inputs -> NHWC xt. 32 px/block, grid 4096.
// blockIdx = p*8 + b  (batch -> XCD swizzle)
// ---------------------------------------------------------------------------
__global__ __launch_bounds__(256) void k_fuse(const float* __restrict__ xi,
                                              const float* __restrict__ xc,
                                              const float* __restrict__ wfT,
                                              float* __restrict__ xt) {
    __shared__ float sW[128 * 64];
    __shared__ float sIn[128 * 32];
    const int t = threadIdx.x;
    const int b = blockIdx.x & 7;
    const int px0 = (blockIdx.x >> 3) * 32;

    {
        const float4* s = (const float4*)wfT;
        float4* d = (float4*)sW;
#pragma unroll
        for (int j = 0; j < 8; ++j) d[t + 256 * j] = s[t + 256 * j];
    }
    {
        float4* d = (float4*)sIn;
#pragma unroll
        for (int j = 0; j < 4; ++j) {
            int idx4 = t + 256 * j;
            int i = idx4 >> 3;
            int p4 = (idx4 & 7) << 2;
            const float* src = (i < 64)
                ? (xi + ((size_t)(b * 64 + i)) * HW_ + px0 + p4)
                : (xc + ((size_t)(b * 64 + (i - 64))) * HW_ + px0 + p4);
            d[idx4] = *(const float4*)src;
        }
    }
    __syncthreads();

    const int o = t & 63;
    const int q = t >> 6;
    float acc[8];
#pragma unroll
    for (int j = 0; j < 8; ++j) acc[j] = 0.f;

    for (int i = 0; i < 128; ++i) {
        const float w = sW[i * 64 + o];
        const float4 a = *(const float4*)&sIn[i * 32 + q * 8];
        const float4 c = *(const float4*)&sIn[i * 32 + q * 8 + 4];
        acc[0] += w * a.x; acc[1] += w * a.y; acc[2] += w * a.z; acc[3] += w * a.w;
        acc[4] += w * c.x; acc[5] += w * c.y; acc[6] += w * c.z; acc[7] += w * c.w;
    }

    float* dst = xt + ((size_t)b * HW_ + px0 + q * 8) * 64 + o;
#pragma unroll
    for (int j = 0; j < 8; ++j) dst[(size_t)j * 64] = acc[j];
}

// ---------------------------------------------------------------------------
// Kernel 2: 3x3 off+mod convs as im2col bf16 MFMA GEMM.
//   M=32 (27 padded), N=64 px (half row), K=576 (k = tap*64+ci).
// Block: 256 thr (4 waves), wave wv owns px tile [h*64+wv*16, +16).
// grid = B*H*2 = 2048, blockIdx = (y*2+h)*8 + b (XCD swizzle).
// LDS sB: [row 0..2][p 0..65][ci, stride 72] bf16 (28512 B) -> 5 blocks/CU.
//   p <-> global x = h*64 + p - 1 (halo, zero-padded at borders).
// B-frag (16x16x32): n15 -> px, q4*8+j -> gk = kc*32+q4*8+j; tap=gk>>6 uniform
// per kc; reads are b128, 16B-aligned (stride 144 B), <=2-way banked (free).
// ---------------------------------------------------------------------------
__global__ __launch_bounds__(256) void k_offmod(const float* __restrict__ xt,
                                                const unsigned short* __restrict__ wrP2,
                                                const float* __restrict__ bOff,
                                                const float* __restrict__ bMod,
                                                float* __restrict__ om) {
    __shared__ unsigned short sB[3 * 66 * 72];   // 28512 B
    const int t = threadIdx.x;
    const int lane = t & 63;
    const int wv = t >> 6;
    const int b = blockIdx.x & 7;
    const int yh = blockIdx.x >> 3;
    const int y = yh >> 1;
    const int h = yh & 1;

    // ---- stage 3 rows x 66 px x 64 ch, fp32 -> bf16 ----
    for (int idx = t; idx < 3 * 66 * 16; idx += 256) {
        const int c4 = idx & 15;
        const int pp = (idx >> 4) % 66;
        const int row = (idx >> 4) / 66;
        const int gx = h * 64 + pp - 1;
        const int gy = y + row - 1;
        float4 v = {0.f, 0.f, 0.f, 0.f};
        if (gx >= 0 && gx < W_ && gy >= 0 && gy < H_)
            v = *(const float4*)&xt[(((size_t)(b * H_ + gy)) * W_ + gx) * 64 + c4 * 4];
        unsigned short* d = &sB[(row * 66 + pp) * 72 + c4 * 4];
        d[0] = f2bf(v.x); d[1] = f2bf(v.y); d[2] = f2bf(v.z); d[3] = f2bf(v.w);
    }
    __syncthreads();

    const int n15 = lane & 15;
    const int q4 = lane >> 4;

    f32x4 acc[2];
    acc[0] = (f32x4){0.f, 0.f, 0.f, 0.f};
    acc[1] = (f32x4){0.f, 0.f, 0.f, 0.f};

#pragma unroll
    for (int kc = 0; kc < 18; ++kc) {
        const int gkb = kc * 32 + q4 * 8;
        const int tap = gkb >> 6;          // uniform across wave per kc
        const int ci = gkb & 63;
        const int row = tap / 3, kx = tap % 3;
        const bf16x8 bf = *(const bf16x8*)&sB[(row * 66 + (wv * 16 + n15 + kx)) * 72 + ci];
        const bf16x8 a0 = *(const bf16x8*)(wrP2 + (((size_t)(kc * 2 + 0) * 64 + lane) * 8));
        const bf16x8 a1 = *(const bf16x8*)(wrP2 + (((size_t)(kc * 2 + 1) * 64 + lane) * 8));
        acc[0] = __builtin_amdgcn_mfma_f32_16x16x32_bf16(a0, bf, acc[0], 0, 0, 0);
        acc[1] = __builtin_amdgcn_mfma_f32_16x16x32_bf16(a1, bf, acc[1], 0, 0, 0);
    }

    // ---- epilogue: D[m = mt*16+q4*4+r][px = h*64 + wv*16 + n15] ----
    const int px = h * 64 + wv * 16 + n15;
    const size_t rec = (((size_t)(b * H_ + y)) * W_ + px) * 28;
#pragma unroll
    for (int mt = 0; mt < 2; ++mt)
#pragma unroll
        for (int r = 0; r < 4; ++r) {
            const int o = mt * 16 + q4 * 4 + r;
            if (o < 18) {
                const float v = acc[mt][r] + bOff[o];
                om[rec + (o >> 1) + ((o & 1) ? 9 : 0)] = v;
            } else if (o < 27) {
                const float z = acc[mt][r] + bMod[o - 18];
                om[rec + 18 + (o - 18)] = 2.f / (1.f + expf(-z));
            }
        }
}

// ---------------------------------------------------------------------------
// Kernel 3: deformable sampling + modulation + bf16 MFMA einsum.
// (unchanged from R2 — one (b,y) row per block, barrier-free tap loop)
// ---------------------------------------------------------------------------
__global__ __launch_bounds__(256) void k_deform(const float* __restrict__ xt,
                                                const float* __restrict__ om,
                                                const unsigned short* __restrict__ wrP,
                                                float* __restrict__ out) {
    __shared__ unsigned short sS2[8 * 1032];   // 16512 B
    __shared__ float sOM[3584];                // 14336 B
    const int t = threadIdx.x;
    const int lane = t & 63;
    const int wv = t >> 6;
    const int b = blockIdx.x & 7;
    const int y = blockIdx.x >> 3;

    const float* xb = xt + (size_t)b * HW_ * 64;

    {
        const float4* src = (const float4*)(om + ((size_t)(b * H_ + y)) * W_ * 28);
        float4* dst = (float4*)sOM;
        for (int idx = t; idx < 896; idx += 256) dst[idx] = src[idx];
    }
    __syncthreads();

    const int n15 = lane & 15;
    const int q4 = lane >> 4;
    const int wpx = wv * 32;
    const int g = lane >> 3;
    const int j7 = lane & 7;

    f32x4 acc[4][2];
#pragma unroll
    for (int mt = 0; mt < 4; ++mt)
#pragma unroll
        for (int nt = 0; nt < 2; ++nt)
            acc[mt][nt] = (f32x4){0.f, 0.f, 0.f, 0.f};

    for (int k = 0; k < 9; ++k) {
        bf16x8 afr[2][4];
#pragma unroll
        for (int kc = 0; kc < 2; ++kc)
#pragma unroll
            for (int mt = 0; mt < 4; ++mt)
                afr[kc][mt] = *(const bf16x8*)(wrP +
                    ((((size_t)((k * 2 + kc) * 4 + mt)) * 64 + lane) * 8));

        const int ky = k / 3 - 1, kx = k % 3 - 1;
#pragma unroll 2
        for (int p = 0; p < 32; ++p) {
            const int px = wpx + p;
            const float dy = sOM[px * 28 + k];
            const float dxv = sOM[px * 28 + 9 + k];
            const float m = sOM[px * 28 + 18 + k];
            const float py  = (float)(y + ky) + dy;
            const float pxe = (float)(px + kx) + dxv;
            const float y0f = floorf(py), x0f = floorf(pxe);
            const int y0i = (int)y0f, x0i = (int)x0f;
            const float wy1 = py - y0f, wx1 = pxe - x0f;
            const float wy0 = 1.f - wy1, wx0 = 1.f - wx1;
            float v = 0.f;
#pragma unroll
            for (int c = 0; c < 4; ++c) {
                const int yyi = y0i + (c >> 1);
                const int xxi = x0i + (c & 1);
                const bool ok = (yyi >= 0) && (yyi < H_) && (xxi >= 0) && (xxi < W_);
                const int yc = min(max(yyi, 0), H_ - 1);
                const int xc = min(max(xxi, 0), W_ - 1);
                const float gv = xb[((size_t)(yc * W_ + xc)) * 64 + lane];
                const float wgt = ((c >> 1) ? wy1 : wy0) * ((c & 1) ? wx1 : wx0);
                v += ok ? gv * wgt : 0.f;
            }
            sS2[g * 1032 + px * 8 + j7] = f2bf(v * m);
        }

#pragma unroll
        for (int kc = 0; kc < 2; ++kc) {
            const bf16x8 b0 = *(const bf16x8*)&sS2[(kc * 4 + q4) * 1032 + (wpx + n15) * 8];
            const bf16x8 b1 = *(const bf16x8*)&sS2[(kc * 4 + q4) * 1032 + (wpx + 16 + n15) * 8];
#pragma unroll
            for (int mt = 0; mt < 4; ++mt) {
                acc[mt][0] = __builtin_amdgcn_mfma_f32_16x16x32_bf16(afr[kc][mt], b0, acc[mt][0], 0, 0, 0);
                acc[mt][1] = __builtin_amdgcn_mfma_f32_16x16x32_bf16(afr[kc][mt], b1, acc[mt][1], 0, 0, 0);
            }
        }
    }

#pragma unroll
    for (int mt = 0; mt < 4; ++mt)
#pragma unroll
        for (int nt = 0; nt < 2; ++nt) {
            const int px = wpx + nt * 16 + n15;
#pragma unroll
            for (int r = 0; r < 4; ++r) {
                const int o = mt * 16 + q4 * 4 + r;
                out[(((size_t)(b * 64 + o)) * H_ + y) * W_ + px] = acc[mt][nt][r];
            }
        }
}

// ---------------------------------------------------------------------------
extern "C" void kernel_launch(void* const* d_in, const int* in_sizes, int n_in,
                              void* d_out, int out_size, void* d_ws, size_t ws_size,
                              hipStream_t stream) {
    const float* x_img  = (const float*)d_in[0];
    const float* x_cont = (const float*)d_in[1];
    const float* w_fuse = (const float*)d_in[2];
    const float* w_off  = (const float*)d_in[3];
    const float* b_off  = (const float*)d_in[4];
    const float* w_mod  = (const float*)d_in[5];
    const float* b_mod  = (const float*)d_in[6];
    const float* w_reg  = (const float*)d_in[7];
    float* out = (float*)d_out;

    float* ws  = (float*)d_ws;
    float* wfT = ws + WS_WFT;
    unsigned short* wrP  = (unsigned short*)(ws + WS_WRP);
    unsigned short* wrP2 = (unsigned short*)(ws + WS_WRP2);
    float* xt  = ws + WS_XT;
    float* om  = ws + WS_OM;

    k_pack<<<32, 256, 0, stream>>>(w_fuse, w_reg, w_off, w_mod, wfT, wrP, wrP2);
    k_fuse<<<B_ * (HW_ / 32), 256, 0, stream>>>(x_img, x_cont, wfT, xt);
    k_offmod<<<B_ * H_ * 2, 256, 0, stream>>>(xt, wrP2, b_off, b_mod, om);
    k_deform<<<B_ * H_, 256, 0, stream>>>(xt, om, wrP, out);
}

// Round 5
// 252.028 us; speedup vs baseline: 2.7318x; 1.4799x over previous
//
#include <hip/hip_runtime.h>
#include <math.h>

// Problem constants
#define B_   8
#define C_   64
#define H_   128
#define W_   128
#define HW_  16384
#define K2_  9

typedef float f32x4 __attribute__((ext_vector_type(4)));
typedef short bf16x8 __attribute__((ext_vector_type(8)));

// Workspace layout (float offsets):
//   wfA  fuse A-frags bf16      @ 0        (8192 us = 4096 f)
//   wrP  deform A-frags bf16    @ 8192     (36864 us = 18432 f)
//   wrP2 offmod A-frags bf16    @ 26624    (18432 us = 9216 f)
//   xt   [B][H][W][64] (NHWC)   @ 45056    (8388608 f)
//   om   [B][y][c 0..27][px]    @ 8433664  (3670016 f)  c: 0-8 dy, 9-17 dx, 18-26 mod
#define WS_WFA  0
#define WS_WRP  8192
#define WS_WRP2 26624
#define WS_XT   45056
#define WS_OM   8433664

static __device__ __forceinline__ unsigned short f2bf(float x) {
    unsigned int u = __float_as_uint(x);
    unsigned int r = (u + 0x7fffu + ((u >> 16) & 1u)) >> 16;   // RNE
    return (unsigned short)r;
}

// ---------------------------------------------------------------------------
// Kernel 0: pack weights into MFMA A-fragment order (16x16x32 bf16).
//   A-frag convention: m = mt*16 + (lane&15), k = kc*32 + (lane>>4)*8 + j.
//   wfA : fuse GEMM,  M=64 (o), K=128 (i)          -> frags (kc 0..3, mt 0..3)
//   wrP : deform einsum, M=64 (o), K=64/tap (i)    -> frags (tap, kc 0..1, mt 0..3)
//   wrP2: offmod conv,  M=32 (27 pad), K=576       -> frags (kc 0..17, mt 0..1)
// ---------------------------------------------------------------------------
__global__ __launch_bounds__(256) void k_pack(const float* __restrict__ wf,
                                              const float* __restrict__ wreg,
                                              const float* __restrict__ wOff,
                                              const float* __restrict__ wMod,
                                              unsigned short* __restrict__ wfA,
                                              unsigned short* __restrict__ wrP,
                                              unsigned short* __restrict__ wrP2) {
    int idx = blockIdx.x * 256 + threadIdx.x;
    if (idx < 1024) {
        int lane = idx & 63, mt = (idx >> 6) & 3, kc = idx >> 8;
        int m = mt * 16 + (lane & 15);
        int kb = kc * 32 + (lane >> 4) * 8;
#pragma unroll
        for (int j = 0; j < 8; ++j)
            wfA[idx * 8 + j] = f2bf(wf[m * 128 + kb + j]);
    }
    if (idx < 4608) {
        int lane = idx & 63, mt = (idx >> 6) & 3, kc = (idx >> 8) & 1, tap = idx >> 9;
        int o = mt * 16 + (lane & 15);
        int ibase = kc * 32 + (lane >> 4) * 8;
#pragma unroll
        for (int j = 0; j < 8; ++j)
            wrP[idx * 8 + j] = f2bf(wreg[(o * 64 + ibase + j) * 9 + tap]);
    }
    if (idx < 2304) {
        int lane = idx & 63, mt = (idx >> 6) & 1, kc = idx >> 7;
        int m = mt * 16 + (lane & 15);
        int gkb = kc * 32 + (lane >> 4) * 8;
#pragma unroll
        for (int j = 0; j < 8; ++j) {
            int gk = gkb + j, tap = gk >> 6, ci = gk & 63;
            float v = 0.f;
            if (m < 18)      v = wOff[(m * 64 + ci) * 9 + tap];
            else if (m < 27) v = wMod[((m - 18) * 64 + ci) * 9 + tap];
            wrP2[idx * 8 + j] = f2bf(v);
        }
    }
}

// ---------------------------------------------------------------------------
// Kernel 1: 1x1 fuse conv as bf16 MFMA GEMM. M=64 (o), N=128 (one row), K=128.
// grid = B*H = 1024, blockIdx = y*8 + b (XCD swizzle). 256 thr / 4 waves,
// wave wv owns px [wv*32, +32).
// sB: B-tile in frag-chunk order [wv][nt][kc][q4][n15][8] bf16 (32 KB);
// staging gathers 8 k-contiguous elems per chunk (64B-coalesced across n15),
// writes one b128 per chunk -> conflict-free; frag reads lane-contiguous.
// ---------------------------------------------------------------------------
__global__ __launch_bounds__(256) void k_fuse(const float* __restrict__ xi,
                                              const float* __restrict__ xc,
                                              const unsigned short* __restrict__ wfA,
                                              float* __restrict__ xt) {
    __shared__ unsigned short sB[2048 * 8];   // 32768 B
    const int t = threadIdx.x;
    const int b = blockIdx.x & 7;
    const int y = blockIdx.x >> 3;
    const size_t rowoff = (size_t)y * W_;

    // ---- stage: 2048 chunks, 8 per thread ----
#pragma unroll
    for (int r = 0; r < 8; ++r) {
        const int cid = t + 256 * r;
        const int n15 = cid & 15;
        const int q4 = (cid >> 4) & 3;
        const int kc = (cid >> 6) & 3;
        const int nt = (cid >> 8) & 1;
        const int wv = cid >> 9;
        const int px = wv * 32 + nt * 16 + n15;
        const int kb = kc * 32 + q4 * 8;
        unsigned short us[8];
#pragma unroll
        for (int j = 0; j < 8; ++j) {
            const int k = kb + j;
            const float v = (k < 64)
                ? xi[((size_t)(b * 64 + k)) * HW_ + rowoff + px]
                : xc[((size_t)(b * 64 + (k - 64))) * HW_ + rowoff + px];
            us[j] = f2bf(v);
        }
        *(bf16x8*)&sB[cid * 8] = *(const bf16x8*)us;
    }
    __syncthreads();

    const int lane = t & 63;
    const int wv = t >> 6;
    const int n15 = lane & 15;
    const int q4 = lane >> 4;

    f32x4 acc[4][2];
#pragma unroll
    for (int mt = 0; mt < 4; ++mt)
#pragma unroll
        for (int nt = 0; nt < 2; ++nt)
            acc[mt][nt] = (f32x4){0.f, 0.f, 0.f, 0.f};

#pragma unroll
    for (int kc = 0; kc < 4; ++kc) {
        const bf16x8 b0 = *(const bf16x8*)&sB[(((((wv * 2 + 0) * 4 + kc) * 4 + q4) * 16) + n15) * 8];
        const bf16x8 b1 = *(const bf16x8*)&sB[(((((wv * 2 + 1) * 4 + kc) * 4 + q4) * 16) + n15) * 8];
#pragma unroll
        for (int mt = 0; mt < 4; ++mt) {
            const bf16x8 a = *(const bf16x8*)(wfA + ((size_t)(kc * 4 + mt) * 64 + lane) * 8);
            acc[mt][0] = __builtin_amdgcn_mfma_f32_16x16x32_bf16(a, b0, acc[mt][0], 0, 0, 0);
            acc[mt][1] = __builtin_amdgcn_mfma_f32_16x16x32_bf16(a, b1, acc[mt][1], 0, 0, 0);
        }
    }

    // epilogue: D[m=o][n=px] -> xt NHWC; 4 consecutive o per lane = 16B store
#pragma unroll
    for (int mt = 0; mt < 4; ++mt)
#pragma unroll
        for (int nt = 0; nt < 2; ++nt) {
            const int px = wv * 32 + nt * 16 + n15;
            float* dst = &xt[(((size_t)b * HW_) + rowoff + px) * 64 + mt * 16 + q4 * 4];
            *(f32x4*)dst = acc[mt][nt];
        }
}

// ---------------------------------------------------------------------------
// Kernel 2: 3x3 off+mod convs as im2col bf16 MFMA GEMM (unchanged math,
// om output layout [c][px]).
// ---------------------------------------------------------------------------
__global__ __launch_bounds__(256) void k_offmod(const float* __restrict__ xt,
                                                const unsigned short* __restrict__ wrP2,
                                                const float* __restrict__ bOff,
                                                const float* __restrict__ bMod,
                                                float* __restrict__ om) {
    __shared__ unsigned short sB[3 * 66 * 72];   // 28512 B
    const int t = threadIdx.x;
    const int lane = t & 63;
    const int wv = t >> 6;
    const int b = blockIdx.x & 7;
    const int yh = blockIdx.x >> 3;
    const int y = yh >> 1;
    const int h = yh & 1;

    for (int idx = t; idx < 3 * 66 * 16; idx += 256) {
        const int c4 = idx & 15;
        const int pp = (idx >> 4) % 66;
        const int row = (idx >> 4) / 66;
        const int gx = h * 64 + pp - 1;
        const int gy = y + row - 1;
        float4 v = {0.f, 0.f, 0.f, 0.f};
        if (gx >= 0 && gx < W_ && gy >= 0 && gy < H_)
            v = *(const float4*)&xt[(((size_t)(b * H_ + gy)) * W_ + gx) * 64 + c4 * 4];
        unsigned short* d = &sB[(row * 66 + pp) * 72 + c4 * 4];
        d[0] = f2bf(v.x); d[1] = f2bf(v.y); d[2] = f2bf(v.z); d[3] = f2bf(v.w);
    }
    __syncthreads();

    const int n15 = lane & 15;
    const int q4 = lane >> 4;

    f32x4 acc[2];
    acc[0] = (f32x4){0.f, 0.f, 0.f, 0.f};
    acc[1] = (f32x4){0.f, 0.f, 0.f, 0.f};

#pragma unroll
    for (int kc = 0; kc < 18; ++kc) {
        const int gkb = kc * 32 + q4 * 8;
        const int tap = gkb >> 6;
        const int ci = gkb & 63;
        const int row = tap / 3, kx = tap % 3;
        const bf16x8 bf = *(const bf16x8*)&sB[(row * 66 + (wv * 16 + n15 + kx)) * 72 + ci];
        const bf16x8 a0 = *(const bf16x8*)(wrP2 + (((size_t)(kc * 2 + 0) * 64 + lane) * 8));
        const bf16x8 a1 = *(const bf16x8*)(wrP2 + (((size_t)(kc * 2 + 1) * 64 + lane) * 8));
        acc[0] = __builtin_amdgcn_mfma_f32_16x16x32_bf16(a0, bf, acc[0], 0, 0, 0);
        acc[1] = __builtin_amdgcn_mfma_f32_16x16x32_bf16(a1, bf, acc[1], 0, 0, 0);
    }

    // epilogue: om[b][y][c][px], c: dy 0-8, dx 9-17, mod 18-26
    const int px = h * 64 + wv * 16 + n15;
    const size_t rec = ((size_t)(b * H_ + y)) * 28 * 128;
#pragma unroll
    for (int mt = 0; mt < 2; ++mt)
#pragma unroll
        for (int r = 0; r < 4; ++r) {
            const int o = mt * 16 + q4 * 4 + r;
            if (o < 18) {
                const int c = (o >> 1) + ((o & 1) ? 9 : 0);
                om[rec + c * 128 + px] = acc[mt][r] + bOff[o];
            } else if (o < 27) {
                const float z = acc[mt][r] + bMod[o - 18];
                om[rec + (18 + (o - 18)) * 128 + px] = 2.f / (1.f + expf(-z));
            }
        }
}

// ---------------------------------------------------------------------------
// Kernel 3: deformable sampling + modulation + bf16 MFMA einsum.
// One (b,y) row per block, 4 waves x 32 px, ZERO barriers (all wave-private).
// Per tap:
//   Phase A (lane = px*2+corner-row): compute 4 (byte-offset, weight) records
//            per px in parallel, write wave-private LDS (1 b128/lane).
//   Phase B (lane = channel): per px read record (broadcast), 4 saddr gathers,
//            4 FMA, f2bf -> sS2 in B-frag order.
//   MFMA: 8 x 16x16x32 bf16 into acc.
// ---------------------------------------------------------------------------
__global__ __launch_bounds__(256) void k_deform(const float* __restrict__ xt,
                                                const float* __restrict__ om,
                                                const unsigned short* __restrict__ wrP,
                                                float* __restrict__ out) {
    __shared__ unsigned short sS2[8 * 1032];       // 16512 B
    __shared__ unsigned int sRec[4 * 32 * 8];      //  4096 B  [wv][px][4x(off,w)]
    const int t = threadIdx.x;
    const int lane = t & 63;
    const int wv = t >> 6;
    const int b = blockIdx.x & 7;
    const int y = blockIdx.x >> 3;

    const char* xbB = (const char*)(xt + (size_t)b * HW_ * 64);
    const float* omr = om + ((size_t)(b * H_ + y)) * 28 * 128;

    const int n15 = lane & 15;
    const int q4 = lane >> 4;
    const int wpx = wv * 32;
    const int g = lane >> 3;
    const int j7 = lane & 7;
    const int pA = lane >> 1;      // phase-A px-local
    const int cp = lane & 1;       // phase-A corner row (y0 / y0+1)

    f32x4 acc[4][2];
#pragma unroll
    for (int mt = 0; mt < 4; ++mt)
#pragma unroll
        for (int nt = 0; nt < 2; ++nt)
            acc[mt][nt] = (f32x4){0.f, 0.f, 0.f, 0.f};

    for (int k = 0; k < 9; ++k) {
        bf16x8 afr[2][4];
#pragma unroll
        for (int kc = 0; kc < 2; ++kc)
#pragma unroll
            for (int mt = 0; mt < 4; ++mt)
                afr[kc][mt] = *(const bf16x8*)(wrP +
                    ((((size_t)((k * 2 + kc) * 4 + mt)) * 64 + lane) * 8));

        const int ky = k / 3 - 1, kx = k % 3 - 1;

        // ---- Phase A: per-px sampling records ----
        {
            const int px = wpx + pA;
            const float dy = omr[k * 128 + px];
            const float dxv = omr[(9 + k) * 128 + px];
            const float m = omr[(18 + k) * 128 + px];
            const float py  = (float)(y + ky) + dy;
            const float pxe = (float)(px + kx) + dxv;
            const float y0f = floorf(py), x0f = floorf(pxe);
            const int y0i = (int)y0f, x0i = (int)x0f;
            const float wy1 = py - y0f, wx1 = pxe - x0f;
            const float wy = cp ? wy1 : (1.f - wy1);
            const float wx0 = 1.f - wx1;
            const int yy = y0i + cp;
            const bool vy = (yy >= 0) && (yy < H_);
            const int yc = min(max(yy, 0), H_ - 1);
            const int x1i = x0i + 1;
            const int xc0 = min(max(x0i, 0), W_ - 1);
            const int xc1 = min(max(x1i, 0), W_ - 1);
            const float w0 = (vy && x0i >= 0 && x0i < W_) ? wy * wx0 * m : 0.f;
            const float w1 = (vy && x1i >= 0 && x1i < W_) ? wy * wx1 * m : 0.f;
            uint4 rec;
            rec.x = (unsigned int)((yc * W_ + xc0) << 8);
            rec.y = __float_as_uint(w0);
            rec.z = (unsigned int)((yc * W_ + xc1) << 8);
            rec.w = __float_as_uint(w1);
            *(uint4*)&sRec[((wv * 32 + pA) * 2 + cp) * 4] = rec;
        }

        // ---- Phase B: gather + combine, lane = channel ----
#pragma unroll 4
        for (int p = 0; p < 32; ++p) {
            const uint4 r0 = *(const uint4*)&sRec[(wv * 32 + p) * 8];
            const uint4 r1 = *(const uint4*)&sRec[(wv * 32 + p) * 8 + 4];
            const float g0 = *(const float*)(xbB + (r0.x + lane * 4));
            const float g1 = *(const float*)(xbB + (r0.z + lane * 4));
            const float g2 = *(const float*)(xbB + (r1.x + lane * 4));
            const float g3 = *(const float*)(xbB + (r1.z + lane * 4));
            const float v = g0 * __uint_as_float(r0.y) + g1 * __uint_as_float(r0.w)
                          + g2 * __uint_as_float(r1.y) + g3 * __uint_as_float(r1.w);
            sS2[g * 1032 + (wpx + p) * 8 + j7] = f2bf(v);
        }

        // ---- MFMA (wave-private B reads) ----
#pragma unroll
        for (int kc = 0; kc < 2; ++kc) {
            const bf16x8 b0 = *(const bf16x8*)&sS2[(kc * 4 + q4) * 1032 + (wpx + n15) * 8];
            const bf16x8 b1 = *(const bf16x8*)&sS2[(kc * 4 + q4) * 1032 + (wpx + 16 + n15) * 8];
#pragma unroll
            for (int mt = 0; mt < 4; ++mt) {
                acc[mt][0] = __builtin_amdgcn_mfma_f32_16x16x32_bf16(afr[kc][mt], b0, acc[mt][0], 0, 0, 0);
                acc[mt][1] = __builtin_amdgcn_mfma_f32_16x16x32_bf16(afr[kc][mt], b1, acc[mt][1], 0, 0, 0);
            }
        }
    }

#pragma unroll
    for (int mt = 0; mt < 4; ++mt)
#pragma unroll
        for (int nt = 0; nt < 2; ++nt) {
            const int px = wpx + nt * 16 + n15;
#pragma unroll
            for (int r = 0; r < 4; ++r) {
                const int o = mt * 16 + q4 * 4 + r;
                out[(((size_t)(b * 64 + o)) * H_ + y) * W_ + px] = acc[mt][nt][r];
            }
        }
}

// ---------------------------------------------------------------------------
extern "C" void kernel_launch(void* const* d_in, const int* in_sizes, int n_in,
                              void* d_out, int out_size, void* d_ws, size_t ws_size,
                              hipStream_t stream) {
    const float* x_img  = (const float*)d_in[0];
    const float* x_cont = (const float*)d_in[1];
    const float* w_fuse = (const float*)d_in[2];
    const float* w_off  = (const float*)d_in[3];
    const float* b_off  = (const float*)d_in[4];
    const float* w_mod  = (const float*)d_in[5];
    const float* b_mod  = (const float*)d_in[6];
    const float* w_reg  = (const float*)d_in[7];
    float* out = (float*)d_out;

    float* ws  = (float*)d_ws;
    unsigned short* wfA  = (unsigned short*)(ws + WS_WFA);
    unsigned short* wrP  = (unsigned short*)(ws + WS_WRP);
    unsigned short* wrP2 = (unsigned short*)(ws + WS_WRP2);
    float* xt  = ws + WS_XT;
    float* om  = ws + WS_OM;

    k_pack<<<18, 256, 0, stream>>>(w_fuse, w_reg, w_off, w_mod, wfA, wrP, wrP2);
    k_fuse<<<B_ * H_, 256, 0, stream>>>(x_img, x_cont, wfA, xt);
    k_offmod<<<B_ * H_ * 2, 256, 0, stream>>>(xt, wrP2, b_off, b_mod, om);
    k_deform<<<B_ * H_, 256, 0, stream>>>(xt, om, wrP, out);
}

// Round 6
// 226.903 us; speedup vs baseline: 3.0343x; 1.1107x over previous
//
#include <hip/hip_runtime.h>
#include <math.h>

// Problem constants
#define B_   8
#define C_   64
#define H_   128
#define W_   128
#define HW_  16384
#define K2_  9

typedef float f32x4 __attribute__((ext_vector_type(4)));
typedef short bf16x8 __attribute__((ext_vector_type(8)));
typedef unsigned short u16x4 __attribute__((ext_vector_type(4)));

// Workspace layout (float offsets):
//   wfA  fuse A-frags bf16      @ 0        (8192 us)
//   wrP  deform A-frags bf16    @ 8192     (36864 us)
//   wrP2 offmod A-frags bf16    @ 26624    (18432 us)
//   xt   [B][H][W][64] bf16     @ 45056    (2097152 us = 1048576 f)
//   om   [B][y][c 0..27][px]    @ 8433664  (3670016 f)  c: 0-8 dy, 9-17 dx, 18-26 mod
#define WS_WFA  0
#define WS_WRP  8192
#define WS_WRP2 26624
#define WS_XT   45056
#define WS_OM   8433664

static __device__ __forceinline__ unsigned short f2bf(float x) {
    unsigned int u = __float_as_uint(x);
    unsigned int r = (u + 0x7fffu + ((u >> 16) & 1u)) >> 16;   // RNE
    return (unsigned short)r;
}
static __device__ __forceinline__ float bf2f(unsigned short u) {
    return __uint_as_float(((unsigned int)u) << 16);
}

// ---------------------------------------------------------------------------
// Kernel 0: pack weights into MFMA A-fragment order (16x16x32 bf16).
//   A-frag convention: m = mt*16 + (lane&15), k = kc*32 + (lane>>4)*8 + j.
// ---------------------------------------------------------------------------
__global__ __launch_bounds__(256) void k_pack(const float* __restrict__ wf,
                                              const float* __restrict__ wreg,
                                              const float* __restrict__ wOff,
                                              const float* __restrict__ wMod,
                                              unsigned short* __restrict__ wfA,
                                              unsigned short* __restrict__ wrP,
                                              unsigned short* __restrict__ wrP2) {
    int idx = blockIdx.x * 256 + threadIdx.x;
    if (idx < 1024) {
        int lane = idx & 63, mt = (idx >> 6) & 3, kc = idx >> 8;
        int m = mt * 16 + (lane & 15);
        int kb = kc * 32 + (lane >> 4) * 8;
#pragma unroll
        for (int j = 0; j < 8; ++j)
            wfA[idx * 8 + j] = f2bf(wf[m * 128 + kb + j]);
    }
    if (idx < 4608) {
        int lane = idx & 63, mt = (idx >> 6) & 3, kc = (idx >> 8) & 1, tap = idx >> 9;
        int o = mt * 16 + (lane & 15);
        int ibase = kc * 32 + (lane >> 4) * 8;
#pragma unroll
        for (int j = 0; j < 8; ++j)
            wrP[idx * 8 + j] = f2bf(wreg[(o * 64 + ibase + j) * 9 + tap]);
    }
    if (idx < 2304) {
        int lane = idx & 63, mt = (idx >> 6) & 1, kc = idx >> 7;
        int m = mt * 16 + (lane & 15);
        int gkb = kc * 32 + (lane >> 4) * 8;
#pragma unroll
        for (int j = 0; j < 8; ++j) {
            int gk = gkb + j, tap = gk >> 6, ci = gk & 63;
            float v = 0.f;
            if (m < 18)      v = wOff[(m * 64 + ci) * 9 + tap];
            else if (m < 27) v = wMod[((m - 18) * 64 + ci) * 9 + tap];
            wrP2[idx * 8 + j] = f2bf(v);
        }
    }
}

// ---------------------------------------------------------------------------
// Kernel 1: 1x1 fuse conv as bf16 MFMA GEMM, LDS-free.
// M=64 (o), N=64 (half row), K=128. grid = B*H*2 = 2048,
// blockIdx = (y*2+h)*8 + b. Wave wv owns px [h*64+wv*16, +16).
// Each lane builds its B-frags directly from global (8 strided dwords per
// frag, 16-lane x 64 B coalesced per j); A-frags from wfA (L1-hot).
// Epilogue: bf16 NHWC, 8 B per store.
// ---------------------------------------------------------------------------
__global__ __launch_bounds__(256) void k_fuse(const float* __restrict__ xi,
                                              const float* __restrict__ xc,
                                              const unsigned short* __restrict__ wfA,
                                              unsigned short* __restrict__ xtb) {
    const int t = threadIdx.x;
    const int lane = t & 63;
    const int wv = t >> 6;
    const int b = blockIdx.x & 7;
    const int yh = blockIdx.x >> 3;
    const int y = yh >> 1;
    const int h = yh & 1;

    const int n15 = lane & 15;
    const int q4 = lane >> 4;
    const int px = h * 64 + wv * 16 + n15;
    const size_t poff = (size_t)y * W_ + px;

    f32x4 acc[4];
#pragma unroll
    for (int mt = 0; mt < 4; ++mt) acc[mt] = (f32x4){0.f, 0.f, 0.f, 0.f};

#pragma unroll
    for (int kc = 0; kc < 4; ++kc) {
        // B-frag: k = kc*32 + q4*8 + j, this lane's px
        const float* src = (kc < 2)
            ? (xi + ((size_t)(b * 64 + kc * 32 + q4 * 8)) * HW_ + poff)
            : (xc + ((size_t)(b * 64 + (kc - 2) * 32 + q4 * 8)) * HW_ + poff);
        unsigned short us[8];
#pragma unroll
        for (int j = 0; j < 8; ++j) us[j] = f2bf(src[(size_t)j * HW_]);
        const bf16x8 bf = *(const bf16x8*)us;
#pragma unroll
        for (int mt = 0; mt < 4; ++mt) {
            const bf16x8 a = *(const bf16x8*)(wfA + ((size_t)(kc * 4 + mt) * 64 + lane) * 8);
            acc[mt] = __builtin_amdgcn_mfma_f32_16x16x32_bf16(a, bf, acc[mt], 0, 0, 0);
        }
    }

    // epilogue: D[m=o][n=px] -> xtb NHWC bf16; 4 consecutive o = 8 B store
#pragma unroll
    for (int mt = 0; mt < 4; ++mt) {
        u16x4 o4;
        o4.x = f2bf(acc[mt][0]); o4.y = f2bf(acc[mt][1]);
        o4.z = f2bf(acc[mt][2]); o4.w = f2bf(acc[mt][3]);
        *(u16x4*)&xtb[((size_t)b * HW_ + poff) * 64 + mt * 16 + q4 * 4] = o4;
    }
}

// ---------------------------------------------------------------------------
// Kernel 2: 3x3 off+mod convs as im2col bf16 MFMA GEMM; xt is now bf16 so
// staging is direct 16 B copies (no conversion). om layout [c][px].
// ---------------------------------------------------------------------------
__global__ __launch_bounds__(256) void k_offmod(const unsigned short* __restrict__ xtb,
                                                const unsigned short* __restrict__ wrP2,
                                                const float* __restrict__ bOff,
                                                const float* __restrict__ bMod,
                                                float* __restrict__ om) {
    __shared__ unsigned short sB[3 * 66 * 72];   // 28512 B
    const int t = threadIdx.x;
    const int lane = t & 63;
    const int wv = t >> 6;
    const int b = blockIdx.x & 7;
    const int yh = blockIdx.x >> 3;
    const int y = yh >> 1;
    const int h = yh & 1;

    for (int idx = t; idx < 3 * 66 * 8; idx += 256) {
        const int c8 = idx & 7;
        const int pp = (idx >> 3) % 66;
        const int row = (idx >> 3) / 66;
        const int gx = h * 64 + pp - 1;
        const int gy = y + row - 1;
        bf16x8 v = {0, 0, 0, 0, 0, 0, 0, 0};
        if (gx >= 0 && gx < W_ && gy >= 0 && gy < H_)
            v = *(const bf16x8*)&xtb[(((size_t)(b * H_ + gy)) * W_ + gx) * 64 + c8 * 8];
        *(bf16x8*)&sB[(row * 66 + pp) * 72 + c8 * 8] = v;
    }
    __syncthreads();

    const int n15 = lane & 15;
    const int q4 = lane >> 4;

    f32x4 acc[2];
    acc[0] = (f32x4){0.f, 0.f, 0.f, 0.f};
    acc[1] = (f32x4){0.f, 0.f, 0.f, 0.f};

#pragma unroll
    for (int kc = 0; kc < 18; ++kc) {
        const int gkb = kc * 32 + q4 * 8;
        const int tap = gkb >> 6;
        const int ci = gkb & 63;
        const int row = tap / 3, kx = tap % 3;
        const bf16x8 bf = *(const bf16x8*)&sB[(row * 66 + (wv * 16 + n15 + kx)) * 72 + ci];
        const bf16x8 a0 = *(const bf16x8*)(wrP2 + (((size_t)(kc * 2 + 0) * 64 + lane) * 8));
        const bf16x8 a1 = *(const bf16x8*)(wrP2 + (((size_t)(kc * 2 + 1) * 64 + lane) * 8));
        acc[0] = __builtin_amdgcn_mfma_f32_16x16x32_bf16(a0, bf, acc[0], 0, 0, 0);
        acc[1] = __builtin_amdgcn_mfma_f32_16x16x32_bf16(a1, bf, acc[1], 0, 0, 0);
    }

    // epilogue: om[b][y][c][px], c: dy 0-8, dx 9-17, mod 18-26
    const int px = h * 64 + wv * 16 + n15;
    const size_t rec = ((size_t)(b * H_ + y)) * 28 * 128;
#pragma unroll
    for (int mt = 0; mt < 2; ++mt)
#pragma unroll
        for (int r = 0; r < 4; ++r) {
            const int o = mt * 16 + q4 * 4 + r;
            if (o < 18) {
                const int c = (o >> 1) + ((o & 1) ? 9 : 0);
                om[rec + c * 128 + px] = acc[mt][r] + bOff[o];
            } else if (o < 27) {
                const float z = acc[mt][r] + bMod[o - 18];
                om[rec + (18 + (o - 18)) * 128 + px] = 2.f / (1.f + expf(-z));
            }
        }
}

// ---------------------------------------------------------------------------
// Kernel 3: deformable sampling + modulation + bf16 MFMA einsum.
// Half-row blocks: grid = B*H*2 = 2048, 4 waves x 16 px, ZERO barriers.
// Per tap:
//   Phase A: 64 lanes = 16 px x 4 corners; each lane computes ONE
//            (byte-offset, weight) pair -> wave-private sRec (uint2).
//   Phase B (lane = channel): per px read 2 uint4 recs (broadcast),
//            4 bf16 gathers (128 B/wave each), combine, f2bf -> sS2.
//   MFMA: 9 taps x 2 kc x 4 mt = 72 x 16x16x32 bf16.
// ---------------------------------------------------------------------------
__global__ __launch_bounds__(256) void k_deform(const unsigned short* __restrict__ xtb,
                                                const float* __restrict__ om,
                                                const unsigned short* __restrict__ wrP,
                                                float* __restrict__ out) {
    __shared__ unsigned short sS2[8 * 520];    // 8320 B
    __shared__ unsigned int sRec[4 * 16 * 8];  // 2048 B  [wv][px16][4x(off,w)]
    const int t = threadIdx.x;
    const int lane = t & 63;
    const int wv = t >> 6;
    const int b = blockIdx.x & 7;
    const int yh = blockIdx.x >> 3;
    const int y = yh >> 1;
    const int h = yh & 1;

    const char* xbB = (const char*)(xtb + (size_t)b * HW_ * 64);
    const float* omr = om + ((size_t)(b * H_ + y)) * 28 * 128;

    const int n15 = lane & 15;
    const int q4 = lane >> 4;
    const int pA = lane >> 2;        // phase-A px-local (0..15)
    const int corner = lane & 3;     // corner: 0=(y0,x0) 1=(y0,x1) 2=(y1,x0) 3=(y1,x1)
    const int cy = corner >> 1, cx = corner & 1;

    f32x4 acc[4];
#pragma unroll
    for (int mt = 0; mt < 4; ++mt) acc[mt] = (f32x4){0.f, 0.f, 0.f, 0.f};

    for (int k = 0; k < 9; ++k) {
        const int ky = k / 3 - 1, kx = k % 3 - 1;

        // ---- Phase A: one (offset, weight) per lane ----
        {
            const int px = h * 64 + wv * 16 + pA;
            const float dy = omr[k * 128 + px];
            const float dxv = omr[(9 + k) * 128 + px];
            const float m = omr[(18 + k) * 128 + px];
            const float py  = (float)(y + ky) + dy;
            const float pxe = (float)(px + kx) + dxv;
            const float y0f = floorf(py), x0f = floorf(pxe);
            const int y0i = (int)y0f, x0i = (int)x0f;
            const float wy1 = py - y0f, wx1 = pxe - x0f;
            const int yy = y0i + cy;
            const int xx = x0i + cx;
            const bool ok = (yy >= 0) && (yy < H_) && (xx >= 0) && (xx < W_);
            const int yc = min(max(yy, 0), H_ - 1);
            const int xc = min(max(xx, 0), W_ - 1);
            const float w = (cy ? wy1 : 1.f - wy1) * (cx ? wx1 : 1.f - wx1) * m;
            uint2 rec;
            rec.x = (unsigned int)((yc * W_ + xc) * 128);   // byte offset (bf16 x 64ch)
            rec.y = __float_as_uint(ok ? w : 0.f);
            *(uint2*)&sRec[((wv * 16 + pA) * 4 + corner) * 2] = rec;
        }

        // ---- Phase B: gather + combine, lane = channel ----
#pragma unroll 4
        for (int p = 0; p < 16; ++p) {
            const uint4 r0 = *(const uint4*)&sRec[(wv * 16 + p) * 8];
            const uint4 r1 = *(const uint4*)&sRec[(wv * 16 + p) * 8 + 4];
            const float g0 = bf2f(*(const unsigned short*)(xbB + (r0.x + lane * 2)));
            const float g1 = bf2f(*(const unsigned short*)(xbB + (r0.z + lane * 2)));
            const float g2 = bf2f(*(const unsigned short*)(xbB + (r1.x + lane * 2)));
            const float g3 = bf2f(*(const unsigned short*)(xbB + (r1.z + lane * 2)));
            const float v = g0 * __uint_as_float(r0.y) + g1 * __uint_as_float(r0.w)
                          + g2 * __uint_as_float(r1.y) + g3 * __uint_as_float(r1.w);
            // sS2[g = ch>>3][local px][ch&7]
            sS2[(lane >> 3) * 520 + (wv * 16 + p) * 8 + (lane & 7)] = f2bf(v);
        }

        // ---- MFMA (wave-private B reads) ----
#pragma unroll
        for (int kc = 0; kc < 2; ++kc) {
            const bf16x8 bf = *(const bf16x8*)&sS2[(kc * 4 + q4) * 520 + (wv * 16 + n15) * 8];
#pragma unroll
            for (int mt = 0; mt < 4; ++mt) {
                const bf16x8 a = *(const bf16x8*)(wrP +
                    ((((size_t)((k * 2 + kc) * 4 + mt)) * 64 + lane) * 8));
                acc[mt] = __builtin_amdgcn_mfma_f32_16x16x32_bf16(a, bf, acc[mt], 0, 0, 0);
            }
        }
    }

    // epilogue: D[o = mt*16 + q4*4 + r][px = h*64 + wv*16 + n15], out NCHW
    const int px = h * 64 + wv * 16 + n15;
#pragma unroll
    for (int mt = 0; mt < 4; ++mt)
#pragma unroll
        for (int r = 0; r < 4; ++r) {
            const int o = mt * 16 + q4 * 4 + r;
            out[(((size_t)(b * 64 + o)) * H_ + y) * W_ + px] = acc[mt][r];
        }
}

// ---------------------------------------------------------------------------
extern "C" void kernel_launch(void* const* d_in, const int* in_sizes, int n_in,
                              void* d_out, int out_size, void* d_ws, size_t ws_size,
                              hipStream_t stream) {
    const float* x_img  = (const float*)d_in[0];
    const float* x_cont = (const float*)d_in[1];
    const float* w_fuse = (const float*)d_in[2];
    const float* w_off  = (const float*)d_in[3];
    const float* b_off  = (const float*)d_in[4];
    const float* w_mod  = (const float*)d_in[5];
    const float* b_mod  = (const float*)d_in[6];
    const float* w_reg  = (const float*)d_in[7];
    float* out = (float*)d_out;

    float* ws  = (float*)d_ws;
    unsigned short* wfA  = (unsigned short*)(ws + WS_WFA);
    unsigned short* wrP  = (unsigned short*)(ws + WS_WRP);
    unsigned short* wrP2 = (unsigned short*)(ws + WS_WRP2);
    unsigned short* xtb  = (unsigned short*)(ws + WS_XT);
    float* om  = ws + WS_OM;

    k_pack<<<18, 256, 0, stream>>>(w_fuse, w_reg, w_off, w_mod, wfA, wrP, wrP2);
    k_fuse<<<B_ * H_ * 2, 256, 0, stream>>>(x_img, x_cont, wfA, xtb);
    k_offmod<<<B_ * H_ * 2, 256, 0, stream>>>(xtb, wrP2, b_off, b_mod, om);
    k_deform<<<B_ * H_ * 2, 256, 0, stream>>>(xtb, om, wrP, out);
}

// Round 7
// 216.548 us; speedup vs baseline: 3.1794x; 1.0478x over previous
//
#include <hip/hip_runtime.h>
#include <math.h>

// Problem constants
#define B_   8
#define C_   64
#define H_   128
#define W_   128
#define HW_  16384
#define K2_  9

typedef float f32x4 __attribute__((ext_vector_type(4)));
typedef short bf16x8 __attribute__((ext_vector_type(8)));
typedef unsigned short u16x4 __attribute__((ext_vector_type(4)));

// Workspace layout (float offsets):
//   wrP  deform A-frags bf16    @ 8192     (36864 us)
//   wrP2 offmod A-frags bf16    @ 26624    (18432 us)
//   xt   [B][H][W][64] bf16     @ 45056    (2097152 us)
//   om   [B][y][c 0..27][px]    @ 8433664  (3670016 f)  c: 0-8 dy, 9-17 dx, 18-26 mod
#define WS_WRP  8192
#define WS_WRP2 26624
#define WS_XT   45056
#define WS_OM   8433664

static __device__ __forceinline__ unsigned short f2bf(float x) {
    unsigned int u = __float_as_uint(x);
    unsigned int r = (u + 0x7fffu + ((u >> 16) & 1u)) >> 16;   // RNE
    return (unsigned short)r;
}
static __device__ __forceinline__ float bf2f(unsigned short u) {
    return __uint_as_float(((unsigned int)u) << 16);
}

// ---------------------------------------------------------------------------
// Kernel 1: 1x1 fuse conv as bf16 MFMA GEMM (LDS A-frag build, direct B loads)
// + weight packing for later kernels folded into blocks 0..17.
// M=64 (o), N=64 (half row), K=128. grid = B*H*2 = 2048,
// blockIdx = (y*2+h)*8 + b. Wave wv owns px [h*64+wv*16, +16).
// A-frag convention (16x16x32): m = mt*16+(lane&15), k = kc*32+(lane>>4)*8+j.
// ---------------------------------------------------------------------------
__global__ __launch_bounds__(256) void k_fuse(const float* __restrict__ xi,
                                              const float* __restrict__ xc,
                                              const float* __restrict__ wf,
                                              const float* __restrict__ wreg,
                                              const float* __restrict__ wOff,
                                              const float* __restrict__ wMod,
                                              unsigned short* __restrict__ xtb,
                                              unsigned short* __restrict__ wrP,
                                              unsigned short* __restrict__ wrP2) {
    __shared__ unsigned short sA[1024 * 8];   // 16 KB: [f=kc*4+mt][lane][8]
    const int t = threadIdx.x;
    const int lane = t & 63;
    const int wv = t >> 6;
    const int b = blockIdx.x & 7;
    const int yh = blockIdx.x >> 3;
    const int y = yh >> 1;
    const int h = yh & 1;

    // ---- pack wrP / wrP2 (blocks 0..17 only; consumed by later kernels) ----
    if (blockIdx.x < 18) {
        const int idx = blockIdx.x * 256 + t;
        if (idx < 4608) {
            int ln = idx & 63, mt = (idx >> 6) & 3, kc = (idx >> 8) & 1, tap = idx >> 9;
            int o = mt * 16 + (ln & 15);
            int ibase = kc * 32 + (ln >> 4) * 8;
#pragma unroll
            for (int j = 0; j < 8; ++j)
                wrP[idx * 8 + j] = f2bf(wreg[(o * 64 + ibase + j) * 9 + tap]);
        }
        if (idx < 2304) {
            int ln = idx & 63, mt = (idx >> 6) & 1, kc = idx >> 7;
            int m = mt * 16 + (ln & 15);
            int gkb = kc * 32 + (ln >> 4) * 8;
#pragma unroll
            for (int j = 0; j < 8; ++j) {
                int gk = gkb + j, tap = gk >> 6, ci = gk & 63;
                float v = 0.f;
                if (m < 18)      v = wOff[(m * 64 + ci) * 9 + tap];
                else if (m < 27) v = wMod[((m - 18) * 64 + ci) * 9 + tap];
                wrP2[idx * 8 + j] = f2bf(v);
            }
        }
    }

    // ---- build fuse A-frags in LDS (each block; 32 f2bf8-chunks /thread/4) --
#pragma unroll
    for (int r = 0; r < 4; ++r) {
        const int c = t + 256 * r;      // chunk 0..1023
        const int f = c >> 6;           // f = kc*4 + mt
        const int ln = c & 63;
        const int mt = f & 3, kc = f >> 2;
        const int m = mt * 16 + (ln & 15);
        const int kb = kc * 32 + (ln >> 4) * 8;
        const float* s = wf + m * 128 + kb;
        unsigned short us[8];
#pragma unroll
        for (int j = 0; j < 8; ++j) us[j] = f2bf(s[j]);
        *(bf16x8*)&sA[c * 8] = *(const bf16x8*)us;
    }
    __syncthreads();

    const int n15 = lane & 15;
    const int q4 = lane >> 4;
    const int px = h * 64 + wv * 16 + n15;
    const size_t poff = (size_t)y * W_ + px;

    f32x4 acc[4];
#pragma unroll
    for (int mt = 0; mt < 4; ++mt) acc[mt] = (f32x4){0.f, 0.f, 0.f, 0.f};

#pragma unroll
    for (int kc = 0; kc < 4; ++kc) {
        const float* src = (kc < 2)
            ? (xi + ((size_t)(b * 64 + kc * 32 + q4 * 8)) * HW_ + poff)
            : (xc + ((size_t)(b * 64 + (kc - 2) * 32 + q4 * 8)) * HW_ + poff);
        unsigned short us[8];
#pragma unroll
        for (int j = 0; j < 8; ++j) us[j] = f2bf(src[(size_t)j * HW_]);
        const bf16x8 bf = *(const bf16x8*)us;
#pragma unroll
        for (int mt = 0; mt < 4; ++mt) {
            const bf16x8 a = *(const bf16x8*)&sA[((kc * 4 + mt) * 64 + lane) * 8];
            acc[mt] = __builtin_amdgcn_mfma_f32_16x16x32_bf16(a, bf, acc[mt], 0, 0, 0);
        }
    }

#pragma unroll
    for (int mt = 0; mt < 4; ++mt) {
        u16x4 o4;
        o4.x = f2bf(acc[mt][0]); o4.y = f2bf(acc[mt][1]);
        o4.z = f2bf(acc[mt][2]); o4.w = f2bf(acc[mt][3]);
        *(u16x4*)&xtb[((size_t)b * HW_ + poff) * 64 + mt * 16 + q4 * 4] = o4;
    }
}

// ---------------------------------------------------------------------------
// Kernel 2: 3x3 off+mod convs as im2col bf16 MFMA GEMM. om layout [c][px].
// ---------------------------------------------------------------------------
__global__ __launch_bounds__(256) void k_offmod(const unsigned short* __restrict__ xtb,
                                                const unsigned short* __restrict__ wrP2,
                                                const float* __restrict__ bOff,
                                                const float* __restrict__ bMod,
                                                float* __restrict__ om) {
    __shared__ unsigned short sB[3 * 66 * 72];   // 28512 B
    const int t = threadIdx.x;
    const int lane = t & 63;
    const int wv = t >> 6;
    const int b = blockIdx.x & 7;
    const int yh = blockIdx.x >> 3;
    const int y = yh >> 1;
    const int h = yh & 1;

    for (int idx = t; idx < 3 * 66 * 8; idx += 256) {
        const int c8 = idx & 7;
        const int pp = (idx >> 3) % 66;
        const int row = (idx >> 3) / 66;
        const int gx = h * 64 + pp - 1;
        const int gy = y + row - 1;
        bf16x8 v = {0, 0, 0, 0, 0, 0, 0, 0};
        if (gx >= 0 && gx < W_ && gy >= 0 && gy < H_)
            v = *(const bf16x8*)&xtb[(((size_t)(b * H_ + gy)) * W_ + gx) * 64 + c8 * 8];
        *(bf16x8*)&sB[(row * 66 + pp) * 72 + c8 * 8] = v;
    }
    __syncthreads();

    const int n15 = lane & 15;
    const int q4 = lane >> 4;

    f32x4 acc[2];
    acc[0] = (f32x4){0.f, 0.f, 0.f, 0.f};
    acc[1] = (f32x4){0.f, 0.f, 0.f, 0.f};

#pragma unroll
    for (int kc = 0; kc < 18; ++kc) {
        const int gkb = kc * 32 + q4 * 8;
        const int tap = gkb >> 6;
        const int ci = gkb & 63;
        const int row = tap / 3, kx = tap % 3;
        const bf16x8 bf = *(const bf16x8*)&sB[(row * 66 + (wv * 16 + n15 + kx)) * 72 + ci];
        const bf16x8 a0 = *(const bf16x8*)(wrP2 + (((size_t)(kc * 2 + 0) * 64 + lane) * 8));
        const bf16x8 a1 = *(const bf16x8*)(wrP2 + (((size_t)(kc * 2 + 1) * 64 + lane) * 8));
        acc[0] = __builtin_amdgcn_mfma_f32_16x16x32_bf16(a0, bf, acc[0], 0, 0, 0);
        acc[1] = __builtin_amdgcn_mfma_f32_16x16x32_bf16(a1, bf, acc[1], 0, 0, 0);
    }

    const int px = h * 64 + wv * 16 + n15;
    const size_t rec = ((size_t)(b * H_ + y)) * 28 * 128;
#pragma unroll
    for (int mt = 0; mt < 2; ++mt)
#pragma unroll
        for (int r = 0; r < 4; ++r) {
            const int o = mt * 16 + q4 * 4 + r;
            if (o < 18) {
                const int c = (o >> 1) + ((o & 1) ? 9 : 0);
                om[rec + c * 128 + px] = acc[mt][r] + bOff[o];
            } else if (o < 27) {
                const float z = acc[mt][r] + bMod[o - 18];
                om[rec + (18 + (o - 18)) * 128 + px] = 2.f / (1.f + __expf(-z));
            }
        }
}

// ---------------------------------------------------------------------------
// Kernel 3: deformable sampling + modulation + bf16 MFMA einsum.
// grid = B*H*2 = 2048, 4 waves x 16 px, ZERO barriers, no sRec LDS.
// Per tap:
//   Phase A: lane = (px 0..15)x(corner 0..3); one (byte-offset, weight) pair
//            kept in REGISTERS.
//   Phase B (lane = channel): records broadcast via v_readlane -> SGPRs;
//            gathers are saddr + lane*2 (zero per-load VALU); combine; f2bf;
//            ds_write_u16 into B-frag order.
//   MFMA: 9 taps x 2 kc x 4 mt = 72 x 16x16x32 bf16.
// ---------------------------------------------------------------------------
__global__ __launch_bounds__(256) void k_deform(const unsigned short* __restrict__ xtb,
                                                const float* __restrict__ om,
                                                const unsigned short* __restrict__ wrP,
                                                float* __restrict__ out) {
    __shared__ unsigned short sS2[8 * 520];    // 8320 B
    const int t = threadIdx.x;
    const int lane = t & 63;
    const int wv = t >> 6;
    const int b = blockIdx.x & 7;
    const int yh = blockIdx.x >> 3;
    const int y = yh >> 1;
    const int h = yh & 1;

    const char* xbB = (const char*)(xtb + (size_t)b * HW_ * 64);
    const float* omr = om + ((size_t)(b * H_ + y)) * 28 * 128;

    const int n15 = lane & 15;
    const int q4 = lane >> 4;
    const int pA = lane >> 2;        // phase-A px-local (0..15)
    const int corner = lane & 3;     // 0=(y0,x0) 1=(y0,x1) 2=(y1,x0) 3=(y1,x1)
    const int cy = corner >> 1, cx = corner & 1;
    const int pxA = h * 64 + wv * 16 + pA;
    const int gwrite = (lane >> 3) * 520 + (lane & 7);

    f32x4 acc[4];
#pragma unroll
    for (int mt = 0; mt < 4; ++mt) acc[mt] = (f32x4){0.f, 0.f, 0.f, 0.f};

    for (int k = 0; k < 9; ++k) {
        const int ky = k / 3 - 1, kx = k % 3 - 1;

        // ---- Phase A: one (offset, weight) per lane, in registers ----
        int rOff;
        int rW;
        {
            const float dy = omr[k * 128 + pxA];
            const float dxv = omr[(9 + k) * 128 + pxA];
            const float m = omr[(18 + k) * 128 + pxA];
            const float py  = (float)(y + ky) + dy;
            const float pxe = (float)(pxA + kx) + dxv;
            const float y0f = floorf(py), x0f = floorf(pxe);
            const int y0i = (int)y0f, x0i = (int)x0f;
            const float wy1 = py - y0f, wx1 = pxe - x0f;
            const int yy = y0i + cy;
            const int xx = x0i + cx;
            const bool ok = (yy >= 0) && (yy < H_) && (xx >= 0) && (xx < W_);
            const int yc = min(max(yy, 0), H_ - 1);
            const int xc = min(max(xx, 0), W_ - 1);
            const float w = (cy ? wy1 : 1.f - wy1) * (cx ? wx1 : 1.f - wx1) * m;
            rOff = (yc * W_ + xc) * 128;     // byte offset (64 ch x bf16)
            rW = (int)__float_as_uint(ok ? w : 0.f);
        }

        // ---- Phase B: lane = channel; records via readlane (SGPR broadcast) --
#pragma unroll
        for (int p = 0; p < 16; ++p) {
            const int l0 = p * 4;
            const unsigned o0 = (unsigned)__builtin_amdgcn_readlane(rOff, l0 + 0);
            const unsigned o1 = (unsigned)__builtin_amdgcn_readlane(rOff, l0 + 1);
            const unsigned o2 = (unsigned)__builtin_amdgcn_readlane(rOff, l0 + 2);
            const unsigned o3 = (unsigned)__builtin_amdgcn_readlane(rOff, l0 + 3);
            const float w0 = __uint_as_float((unsigned)__builtin_amdgcn_readlane(rW, l0 + 0));
            const float w1 = __uint_as_float((unsigned)__builtin_amdgcn_readlane(rW, l0 + 1));
            const float w2 = __uint_as_float((unsigned)__builtin_amdgcn_readlane(rW, l0 + 2));
            const float w3 = __uint_as_float((unsigned)__builtin_amdgcn_readlane(rW, l0 + 3));
            const unsigned short* b0 = (const unsigned short*)(xbB + o0);
            const unsigned short* b1 = (const unsigned short*)(xbB + o1);
            const unsigned short* b2 = (const unsigned short*)(xbB + o2);
            const unsigned short* b3 = (const unsigned short*)(xbB + o3);
            const float v = bf2f(b0[lane]) * w0 + bf2f(b1[lane]) * w1
                          + bf2f(b2[lane]) * w2 + bf2f(b3[lane]) * w3;
            sS2[gwrite + (wv * 16 + p) * 8] = f2bf(v);
        }

        // ---- MFMA (wave-private B reads) ----
#pragma unroll
        for (int kc = 0; kc < 2; ++kc) {
            const bf16x8 bf = *(const bf16x8*)&sS2[(kc * 4 + q4) * 520 + (wv * 16 + n15) * 8];
#pragma unroll
            for (int mt = 0; mt < 4; ++mt) {
                const bf16x8 a = *(const bf16x8*)(wrP +
                    ((((size_t)((k * 2 + kc) * 4 + mt)) * 64 + lane) * 8));
                acc[mt] = __builtin_amdgcn_mfma_f32_16x16x32_bf16(a, bf, acc[mt], 0, 0, 0);
            }
        }
    }

    // epilogue: D[o = mt*16 + q4*4 + r][px = h*64 + wv*16 + n15], out NCHW
    const int px = h * 64 + wv * 16 + n15;
#pragma unroll
    for (int mt = 0; mt < 4; ++mt)
#pragma unroll
        for (int r = 0; r < 4; ++r) {
            const int o = mt * 16 + q4 * 4 + r;
            out[(((size_t)(b * 64 + o)) * H_ + y) * W_ + px] = acc[mt][r];
        }
}

// ---------------------------------------------------------------------------
extern "C" void kernel_launch(void* const* d_in, const int* in_sizes, int n_in,
                              void* d_out, int out_size, void* d_ws, size_t ws_size,
                              hipStream_t stream) {
    const float* x_img  = (const float*)d_in[0];
    const float* x_cont = (const float*)d_in[1];
    const float* w_fuse = (const float*)d_in[2];
    const float* w_off  = (const float*)d_in[3];
    const float* b_off  = (const float*)d_in[4];
    const float* w_mod  = (const float*)d_in[5];
    const float* b_mod  = (const float*)d_in[6];
    const float* w_reg  = (const float*)d_in[7];
    float* out = (float*)d_out;

    float* ws  = (float*)d_ws;
    unsigned short* wrP  = (unsigned short*)(ws + WS_WRP);
    unsigned short* wrP2 = (unsigned short*)(ws + WS_WRP2);
    unsigned short* xtb  = (unsigned short*)(ws + WS_XT);
    float* om  = ws + WS_OM;

    k_fuse<<<B_ * H_ * 2, 256, 0, stream>>>(x_img, x_cont, w_fuse, w_reg, w_off,
                                            w_mod, xtb, wrP, wrP2);
    k_offmod<<<B_ * H_ * 2, 256, 0, stream>>>(xtb, wrP2, b_off, b_mod, om);
    k_deform<<<B_ * H_ * 2, 256, 0, stream>>>(xtb, om, wrP, out);
}